// Round 14
// baseline (688.988 us; speedup 1.0000x reference)
//
#include <hip/hip_runtime.h>

// Problem constants
#define CIN  128
#define CO   256
#define HIN  56
#define WIN  56
#define P    784     // 28*28
#define HWIN 3136    // 56*56
#define PERT 200704  // CO*P

typedef __attribute__((ext_vector_type(4))) float f32x4;
typedef __attribute__((ext_vector_type(4))) int   i32x4;

__device__ __forceinline__ i32x4 mfma_i8_64(i32x4 a, i32x4 b, i32x4 c) {
    return __builtin_amdgcn_mfma_i32_16x16x64_i8(a, b, c, 0, 0, 0);
}

// async global->LDS, 16B per lane; LDS dest = wave-uniform base + lane*16
__device__ __forceinline__ void gld_lds16(const void* g, void* l) {
    __builtin_amdgcn_global_load_lds(
        (const __attribute__((address_space(1))) void*)g,
        (__attribute__((address_space(3))) void*)l, 16, 0, 0);
}

// ---------------------------------------------------------------------------
// prepA (1 launch): bias folds + per-co quant scales for w1 and w2/wd.
// ---------------------------------------------------------------------------
__global__ __launch_bounds__(256) void k_prepA(
    const float* __restrict__ g1, const float* __restrict__ b1,
    const float* __restrict__ m1, const float* __restrict__ v1,
    const float* __restrict__ g2, const float* __restrict__ b2,
    const float* __restrict__ m2, const float* __restrict__ v2,
    const float* __restrict__ gd, const float* __restrict__ bd,
    const float* __restrict__ md, const float* __restrict__ vd,
    const float* __restrict__ w1, const float* __restrict__ w2,
    const float* __restrict__ wd,
    float* __restrict__ bias1, float* __restrict__ bias2,
    float* __restrict__ qscale1, float* __restrict__ scale1,
    float* __restrict__ qscale2, float* __restrict__ scale2)
{
    const int bid = blockIdx.x;
    if (bid == 0) {
        int co = threadIdx.x;
        float inv1 = g1[co] / sqrtf(v1[co] + 1e-5f);
        float inv2 = g2[co] / sqrtf(v2[co] + 1e-5f);
        float invd = gd[co] / sqrtf(vd[co] + 1e-5f);
        bias1[co] = fmaf(-m1[co], inv1, b1[co]);
        bias2[co] = fmaf(-m2[co], inv2, b2[co]) + fmaf(-md[co], invd, bd[co]);
        return;
    }
    const int lane = threadIdx.x & 63;
    if (bid <= 64) {                              // w1 scale: co 0..255
        int co = (bid - 1) * 4 + (threadIdx.x >> 6);
        float iv = g1[co] / sqrtf(v1[co] + 1e-5f);
        float m = 0.f;
        for (int k = lane; k < 1152; k += 64)
            m = fmaxf(m, fabsf(w1[(size_t)co * 1152 + k] * iv));
#pragma unroll
        for (int off = 32; off > 0; off >>= 1)
            m = fmaxf(m, __shfl_xor(m, off));
        if (lane == 0) {
            int s = (int)floorf(log2f(8355000.0f / m));
            if (s > 44) s = 44;
            qscale1[co] = ldexpf(1.0f, s);
            scale1[co]  = ldexpf(1.0f, -s);
        }
    } else {                                      // w2/wd shared scale
        int co = (bid - 65) * 4 + (threadIdx.x >> 6);
        float iv2 = g2[co] / sqrtf(v2[co] + 1e-5f);
        float ivd = gd[co] / sqrtf(vd[co] + 1e-5f);
        float m = 0.f;
        for (int k = lane; k < 2304; k += 64)
            m = fmaxf(m, fabsf(w2[(size_t)co * 2304 + k] * iv2));
        for (int k = lane; k < 128; k += 64)
            m = fmaxf(m, fabsf(wd[(size_t)co * 128 + k] * ivd));
#pragma unroll
        for (int off = 32; off > 0; off >>= 1)
            m = fmaxf(m, __shfl_xor(m, off));
        if (lane == 0) {
            int s = (int)floorf(log2f(8355000.0f / m));
            if (s > 40) s = 40;
            qscale2[co] = ldexpf(1.0f, s);
            scale2[co]  = ldexpf(1.0f, -s);
        }
    }
}

// ---------------------------------------------------------------------------
// prepB (1 launch): i8 digit-plane repacks (w1 / w2 / wd) + input bit-pack.
// W = a*2^16 + b*2^8 + c exactly; per-co power-of-two scale from prepA.
// ---------------------------------------------------------------------------
__global__ __launch_bounds__(256) void k_prepB(
    const float* __restrict__ w1, const float* __restrict__ w2,
    const float* __restrict__ wd,
    const float* __restrict__ n1g, const float* __restrict__ n1v,
    const float* __restrict__ n2g, const float* __restrict__ n2v,
    const float* __restrict__ ndg, const float* __restrict__ ndv,
    const float* __restrict__ qscale1, const float* __restrict__ qscale2,
    signed char* __restrict__ pa, signed char* __restrict__ pb,
    signed char* __restrict__ pc,
    signed char* __restrict__ p2a, signed char* __restrict__ p2b,
    signed char* __restrict__ p2c,
    signed char* __restrict__ pda, signed char* __restrict__ pdb,
    signed char* __restrict__ pdc,
    const float* __restrict__ x, unsigned int* __restrict__ xt_p)
{
    const int bid = blockIdx.x;
    if (bid < 72) {                               // w1 -> [tap9][kg2][cf16][64][16]
        int i = bid * 256 + threadIdx.x;
        if (i >= 18432) return;
        int tap = i >> 11;
        int r   = i & 2047;
        int kg  = r >> 10;
        int r2  = r & 1023;
        int cf  = r2 >> 6;
        int lane = r2 & 63;
        int co  = cf * 16 + (lane & 15);
        int ci0 = kg * 64 + (lane >> 4) * 16;
        float iv = n1g[co] / sqrtf(n1v[co] + 1e-5f);
        float q  = qscale1[co];
#pragma unroll
        for (int j = 0; j < 16; j++) {
            float w = w1[((size_t)co * CIN + ci0 + j) * 9 + tap] * iv;
            int W = __float2int_rn(w * q);
            int d0 = ((W & 0xFF) ^ 0x80) - 0x80;  W = (W - d0) / 256;
            int d1 = ((W & 0xFF) ^ 0x80) - 0x80;  W = (W - d1) / 256;
            size_t idx = (size_t)i * 16 + j;
            pa[idx] = (signed char)W;
            pb[idx] = (signed char)d1;
            pc[idx] = (signed char)d0;
        }
    } else if (bid < 216) {                       // w2 -> [tap9][kg4][cf16][64][16]
        int i = (bid - 72) * 256 + threadIdx.x;
        int tap = i >> 12;
        int r   = i & 4095;
        int kg  = r >> 10;
        int r2  = r & 1023;
        int cf  = r2 >> 6;
        int lane = r2 & 63;
        int co  = cf * 16 + (lane & 15);
        int ci0 = kg * 64 + (lane >> 4) * 16;
        float iv = n2g[co] / sqrtf(n2v[co] + 1e-5f);
        float q  = qscale2[co];
#pragma unroll
        for (int j = 0; j < 16; j++) {
            float w = w2[((size_t)co * CO + ci0 + j) * 9 + tap] * iv;
            int W = __float2int_rn(w * q);
            int d0 = ((W & 0xFF) ^ 0x80) - 0x80;  W = (W - d0) / 256;
            int d1 = ((W & 0xFF) ^ 0x80) - 0x80;  W = (W - d1) / 256;
            size_t idx = (size_t)i * 16 + j;
            p2a[idx] = (signed char)W;
            p2b[idx] = (signed char)d1;
            p2c[idx] = (signed char)d0;
        }
    } else if (bid < 224) {                       // wd -> [kg2][cf16][64][16]
        int i = (bid - 216) * 256 + threadIdx.x;
        int kg  = i >> 10;
        int r2  = i & 1023;
        int cf  = r2 >> 6;
        int lane = r2 & 63;
        int co  = cf * 16 + (lane & 15);
        int ci0 = kg * 64 + (lane >> 4) * 16;
        float iv = ndg[co] / sqrtf(ndv[co] + 1e-5f);
        float q  = qscale2[co];
#pragma unroll
        for (int j = 0; j < 16; j++) {
            float w = wd[(size_t)co * CIN + ci0 + j] * iv;
            int W = __float2int_rn(w * q);
            int d0 = ((W & 0xFF) ^ 0x80) - 0x80;  W = (W - d0) / 256;
            int d1 = ((W & 0xFF) ^ 0x80) - 0x80;  W = (W - d1) / 256;
            size_t idx = (size_t)i * 16 + j;
            pda[idx] = (signed char)W;
            pdb[idx] = (signed char)d1;
            pdc[idx] = (signed char)d0;
        }
    } else {                                      // pack x -> bitmask
        int i = (bid - 224) * 256 + threadIdx.x;  // ((n*4 + w)*3136 + pos)
        int pos = i % HWIN;
        int nw  = i / HWIN;
        int w   = nw & 3;
        int n   = nw >> 2;
        const float* xp = x + ((size_t)n * CIN + w * 32) * HWIN + pos;
        unsigned int word = 0;
#pragma unroll
        for (int ci = 0; ci < 32; ci++)
            if (__builtin_nontemporal_load(&xp[(size_t)ci * HWIN]) != 0.f)
                word |= (1u << ci);
        xt_p[((size_t)n * HWIN + pos) * 4 + w] = word;
    }
}

// ---------------------------------------------------------------------------
// conv1 3x3 s2 p1 via i8 MFMA (K=64) on bit-packed spikes, 3 digit planes.
// R9-verified inline nibble-spread + R13-verified XCD swizzle (kept: conv1's
// per-XCD working set xt_p slice 0.8 MB + w1 planes 0.9 MB fits 4 MB L2 ->
// measured ~31 us gain; conv2's 5.9 MB set thrashed, so swizzle is conv1-only).
// ---------------------------------------------------------------------------
__global__ __launch_bounds__(256) void k_conv1_mfma(
    const unsigned int* __restrict__ xt_p,       // [128][3136][4]
    const signed char* __restrict__ pa,          // [9][2][16][64][16]
    const signed char* __restrict__ pb,
    const signed char* __restrict__ pc,
    const float* __restrict__ scale1,
    const float* __restrict__ bias1,
    float* __restrict__ out)                     // [128][256][784] pre-act
{
    __shared__ unsigned int XWP[2][522 * 2];     // [kg][row 9][col 58][2 words]

    const int bid  = blockIdx.x;
    const int swz  = (bid & 7) * 112 + (bid >> 3);   // XCD-contiguous remap
    const int n    = swz / 7;
    const int rt   = swz - n * 7;
    const int r0   = rt * 4;
    const int tid  = threadIdx.x;
    const int wave = tid >> 6;
    const int lane = tid & 63;
    const int l15  = lane & 15;
    const int quad = lane >> 4;
    const int cf   = blockIdx.y * 4 + wave;      // one cf (16 co) per wave

    const unsigned int* xp_n = xt_p + (size_t)n * HWIN * 4;
    for (int i = tid; i < 513; i += 256) {
        int row = i / 57, c = i - row * 57;
        int irow = 2 * r0 - 1 + row;             // [-1, 55]
        int iw   = c - 1;                        // [-1, 55]
        uint4 val = {0u, 0u, 0u, 0u};
        if (irow >= 0 && iw >= 0)
            val = *(const uint4*)(xp_n + (size_t)(irow * WIN + iw) * 4);
        int base = row * 58 + c;
        XWP[0][base * 2 + 0] = val.x;            // ci  0..31
        XWP[0][base * 2 + 1] = val.y;            // ci 32..63
        XWP[1][base * 2 + 0] = val.z;            // ci 64..95
        XWP[1][base * 2 + 1] = val.w;            // ci 96..127
    }
    __syncthreads();

    int ib[7];
#pragma unroll
    for (int f = 0; f < 7; f++) {
        int pos = f * 16 + l15;
        int rr = pos / 28, cc = pos - rr * 28;
        ib[f] = (2 * rr) * 58 + 2 * cc;          // + kh*58 + kw per tap
    }

    const int  qh = quad >> 1;                   // which word of the pair
    const int  ql = (quad & 1) * 16;             // bit offset within word

    i32x4 accA[7], accB[7], accC[7];
#pragma unroll
    for (int f = 0; f < 7; f++) {
        accA[f] = (i32x4){0, 0, 0, 0};
        accB[f] = (i32x4){0, 0, 0, 0};
        accC[f] = (i32x4){0, 0, 0, 0};
    }

    i32x4 wa, wb, wc, na, nb, nc;
    {
        size_t b0 = (size_t)cf * 1024 + lane * 16;   // tap=0, kg=0
        wa = *(const i32x4*)(pa + b0);
        wb = *(const i32x4*)(pb + b0);
        wc = *(const i32x4*)(pc + b0);
        na = wa; nb = wb; nc = wc;
    }

#pragma unroll
    for (int kg = 0; kg < 2; kg++) {
#pragma unroll
        for (int tap = 0; tap < 9; tap++) {
            int rd = kg * 9 + tap;
            if (rd < 17) {                       // prefetch next (kg,tap)
                int rn = rd + 1, kn = rn / 9, tn = rn - kn * 9;
                size_t b0 = ((size_t)(tn * 2 + kn) * 16 + cf) * 1024 + lane * 16;
                na = *(const i32x4*)(pa + b0);
                nb = *(const i32x4*)(pb + b0);
                nc = *(const i32x4*)(pc + b0);
            }
            const int kh = tap / 3, kw = tap - kh * 3;
            const int tapoff = kh * 58 + kw;
#pragma unroll
            for (int f = 0; f < 7; f++) {
                int base = ib[f] + tapoff;
                uint2 pr = *(const uint2*)&XWP[kg][base * 2];
                unsigned int w32  = qh ? pr.y : pr.x;
                unsigned int bits = (w32 >> ql) & 0xFFFFu;
                // nibble -> 4 bytes 0/1 spread: (n * 0x00204081) & 0x01010101
                uint4 u;
                u.x = ((bits & 15u)         * 0x00204081u) & 0x01010101u;
                u.y = (((bits >> 4) & 15u)  * 0x00204081u) & 0x01010101u;
                u.z = (((bits >> 8) & 15u)  * 0x00204081u) & 0x01010101u;
                u.w = ((bits >> 12)         * 0x00204081u) & 0x01010101u;
                union { uint4 q; i32x4 v; } cv;
                cv.q = u;
                __builtin_amdgcn_s_setprio(1);
                accA[f] = mfma_i8_64(wa, cv.v, accA[f]);
                accB[f] = mfma_i8_64(wb, cv.v, accB[f]);
                accC[f] = mfma_i8_64(wc, cv.v, accC[f]);
                __builtin_amdgcn_s_setprio(0);
            }
            wa = na; wb = nb; wc = nc;
        }
    }

#pragma unroll
    for (int f = 0; f < 7; f++) {
        int pg = rt * 112 + f * 16 + l15;
#pragma unroll
        for (int reg = 0; reg < 4; reg++) {
            int co = cf * 16 + quad * 4 + reg;
            float hi = (float)accA[f][reg];
            float mi = (float)accB[f][reg];
            float lo = (float)accC[f][reg];
            float val = fmaf(hi, 65536.f, fmaf(mi, 256.f, lo));
            __builtin_nontemporal_store(
                fmaf(val, scale1[co], bias1[co]),
                &out[((size_t)n * CO + co) * P + pg]);
        }
    }
}

// ---------------------------------------------------------------------------
// LIF1 + transpose: pre1 [16][8][256][784] fp32 ->
// spike bytes st [n][kg 4][pos 784][64 ci] u8, with the 4 16B ci-sub-blocks
// of each pos line stored XOR-rotated by f8(pos) = (((oh+1)*30+ow+1)>>1)&3
// so conv2's DMA-landed LDS reads are conflict-free. NT loads on the
// streaming read-once pre1 keep spike_t writes L2-resident for conv2.
// ---------------------------------------------------------------------------
__global__ __launch_bounds__(256) void k_lif1t(
    const float* __restrict__ pre, unsigned char* __restrict__ st)
{
    __shared__ unsigned short T[16 * 68];
    const int b   = blockIdx.x;
    const int co0 = blockIdx.y * 64;
    const int kg  = blockIdx.y;
    const int p0  = blockIdx.z * 16;
    const int tid  = threadIdx.x;
    const int pcol = tid & 15;
    const int g    = tid >> 4;
    const int pos = p0 + g;
    const int oh  = pos / 28, ow = pos - oh * 28;
    const int f8  = ((((oh + 1) * 30 + ow + 1) >> 1) & 3);
    const int no  = (pcol >> 2) ^ f8;            // rotated 16B sub-block
    const int wb  = (pcol & 3) * 4;              // byte offset in sub-block
    float v[4] = {0.f, 0.f, 0.f, 0.f};
    for (int t = 0; t < 8; t++) {
        const float* src = pre + (((size_t)(b * 8 + t)) * CO + co0) * P + p0;
        unsigned short s[4];
#pragma unroll
        for (int j = 0; j < 4; j++) {
            int co = g + 16 * j;
            float xv = __builtin_nontemporal_load(&src[(size_t)co * P + pcol]);
            v[j] = v[j] + (xv - v[j]) * 0.5f;
            bool sp = v[j] > 1.0f;
            s[j] = sp ? 1 : 0;
            if (sp) v[j] = 0.f;
        }
        __syncthreads();
#pragma unroll
        for (int j = 0; j < 4; j++) T[pcol * 68 + g + 16 * j] = s[j];
        __syncthreads();
        unsigned char* dst = st + (((size_t)(b * 8 + t) * 4 + kg) * P + pos) * 64
                               + no * 16 + wb;
        uchar4 ov;
        ov.x = (unsigned char)T[g * 68 + pcol * 4 + 0];
        ov.y = (unsigned char)T[g * 68 + pcol * 4 + 1];
        ov.z = (unsigned char)T[g * 68 + pcol * 4 + 2];
        ov.w = (unsigned char)T[g * 68 + pcol * 4 + 3];
        *(uchar4*)dst = ov;
    }
}

// ---------------------------------------------------------------------------
// conv2 3x3 s1 p1 + ds 1x1 s2 via i8 MFMA (K=64), 3 digit planes, BN folded.
// R11-verified g=2 version VERBATIM (204 us): full unroll + NT stores +
// dw-hoist + setprio, identity block mapping. R13's XCD swizzle REGRESSED
// here (+52 us): conv2's per-XCD working set (spikes 3.2 MB + w2 1.8 MB +
// xt_p 0.8 MB ~ 5.9 MB) exceeds the 4 MB L2 -> thrash. No swizzle.
// ---------------------------------------------------------------------------
__global__ __launch_bounds__(256) void k_conv2_mfma(
    const unsigned char* __restrict__ spike_t,   // [128][4][784][64] rotated
    const unsigned int* __restrict__ xt_p,       // [128][3136][4]
    const signed char* __restrict__ p2a,         // [9][4][16][64][16]
    const signed char* __restrict__ p2b,
    const signed char* __restrict__ p2c,
    const signed char* __restrict__ pda,         // [2][16][64][16]
    const signed char* __restrict__ pdb,
    const signed char* __restrict__ pdc,
    const float* __restrict__ scale2,
    const float* __restrict__ bias2,
    float* __restrict__ out)                     // [128][256][784]
{
    __shared__ unsigned char SB[2 * 11520];      // 2 bufs; pos line = 64 B
    __shared__ unsigned int  XW2[4 * 112];       // ds bit-words [word][112 pos]

    const int n    = blockIdx.x / 7;
    const int rt   = blockIdx.x - n * 7;
    const int r0   = rt * 4;
    const int tid  = threadIdx.x;
    const int wave = tid >> 6;
    const int lane = tid & 63;
    const int l15  = lane & 15;
    const int quad = lane >> 4;
    const int cf0  = blockIdx.y * 8 + wave * 2;  // 2 cf (32 co) per wave

    // zero both spike buffers (halo protocol) + stage ds bit-words
    {
        uint4 z = {0u, 0u, 0u, 0u};
        for (int i = tid; i < 1440; i += 256) ((uint4*)SB)[i] = z;
    }
    for (int i = tid; i < 112; i += 256) {
        int r = i / 28, c = i - r * 28;
        uint4 w4 = *(const uint4*)(xt_p + ((size_t)n * HWIN
                    + (2 * (r0 + r)) * WIN + 2 * c) * 4);
        XW2[0 * 112 + i] = w4.x;
        XW2[1 * 112 + i] = w4.y;
        XW2[2 * 112 + i] = w4.z;
        XW2[3 * 112 + i] = w4.w;
    }
    __syncthreads();                              // zeros + XW2 visible

    // ds-phase weight regs FIRST (older than the DMA in vmcnt order, so the
    // ds phase does not wait for the spike DMA queue to drain)
    i32x4 dw0[3][2], dw1[3][2];                  // [plane][g] for kg=0,1
#pragma unroll
    for (int g = 0; g < 2; g++) {
        size_t b0 = ((size_t)cf0 + g) * 1024 + (size_t)lane * 16;
        dw0[0][g] = *(const i32x4*)(pda + b0);
        dw0[1][g] = *(const i32x4*)(pdb + b0);
        dw0[2][g] = *(const i32x4*)(pdc + b0);
        size_t b1 = ((size_t)(16 + cf0) + g) * 1024 + (size_t)lane * 16;
        dw1[0][g] = *(const i32x4*)(pda + b1);
        dw1[1][g] = *(const i32x4*)(pdb + b1);
        dw1[2][g] = *(const i32x4*)(pdc + b1);
    }

    // DMA geometry: idx = wave*3+k in [0,12); row = idx>>1, half = idx&1
    int  g_irow[3], g_lds[3];
    bool g_ok[3];
    int  g_half[3];
#pragma unroll
    for (int k = 0; k < 3; k++) {
        int idx  = wave * 3 + k;
        int row  = idx >> 1, half = idx & 1;
        int irow = r0 - 1 + row;
        g_irow[k] = irow;
        g_half[k] = half;
        g_ok[k]   = ((unsigned)irow < 28u) && (half == 0 || lane < 48);
        g_lds[k]  = row * 1920 + 64 + half * 1024;   // wave-uniform
    }
    const char* sp_n = (const char*)spike_t + (size_t)n * 4 * P * 64;

    // issue chunk-0 DMA now; latency hides under the ds phase below
#pragma unroll
    for (int k = 0; k < 3; k++)
        if (g_ok[k])
            gld_lds16(sp_n + (size_t)g_irow[k] * 1792 + g_half[k] * 1024 + lane * 16,
                      (char*)SB + g_lds[k]);

    int ib[7];
#pragma unroll
    for (int f = 0; f < 7; f++) {
        int pos = f * 16 + l15;
        int rr = pos / 28, cc = pos - rr * 28;
        ib[f] = rr * 30 + cc;                    // + kh*30 + kw per tap
    }

    i32x4 acc[3][2][7];                          // [plane][g][f]
#pragma unroll
    for (int p = 0; p < 3; p++)
#pragma unroll
        for (int g = 0; g < 2; g++)
#pragma unroll
            for (int f = 0; f < 7; f++) acc[p][g][f] = (i32x4){0, 0, 0, 0};

    // ---- ds phase (acc init): bit-unpack from XW2, dw regs die after ----
#pragma unroll
    for (int kg = 0; kg < 2; kg++) {
        const int wsel = (kg * 2 + (quad >> 1)) * 112;
        const int shv  = (quad & 1) * 16;
#pragma unroll
        for (int f = 0; f < 7; f++) {
            unsigned int w32  = XW2[wsel + f * 16 + l15];
            unsigned int bits = (w32 >> shv) & 0xFFFFu;
            uint4 u;
            u.x = ((bits & 15u)         * 0x00204081u) & 0x01010101u;
            u.y = (((bits >> 4) & 15u)  * 0x00204081u) & 0x01010101u;
            u.z = (((bits >> 8) & 15u)  * 0x00204081u) & 0x01010101u;
            u.w = ((bits >> 12)         * 0x00204081u) & 0x01010101u;
            union { uint4 q; i32x4 v; } cv;
            cv.q = u;
            __builtin_amdgcn_s_setprio(1);
#pragma unroll
            for (int g = 0; g < 2; g++) {
                acc[0][g][f] = mfma_i8_64(kg ? dw1[0][g] : dw0[0][g], cv.v, acc[0][g][f]);
                acc[1][g][f] = mfma_i8_64(kg ? dw1[1][g] : dw0[1][g], cv.v, acc[1][g][f]);
                acc[2][g][f] = mfma_i8_64(kg ? dw1[2][g] : dw0[2][g], cv.v, acc[2][g][f]);
            }
            __builtin_amdgcn_s_setprio(0);
        }
    }
    __syncthreads();                              // drains chunk-0 DMA too

    // ---- main conv loop, double-buffered DMA, weight reg prefetch ----
    i32x4 cw[2][3], nx[2][3];
#pragma unroll
    for (int g = 0; g < 2; g++) {
        size_t b0 = ((size_t)(cf0 + g)) * 1024 + (size_t)lane * 16;  // tap0,kg0
        cw[g][0] = *(const i32x4*)(p2a + b0);
        cw[g][1] = *(const i32x4*)(p2b + b0);
        cw[g][2] = *(const i32x4*)(p2c + b0);
        nx[g][0] = cw[g][0]; nx[g][1] = cw[g][1]; nx[g][2] = cw[g][2];
    }

#pragma unroll
    for (int c = 0; c < 4; c++) {
        if (c < 3) {                              // async stage chunk c+1
            const char* base = sp_n + (size_t)(c + 1) * 50176;
            char* dstb = (char*)SB + ((c + 1) & 1) * 11520;
#pragma unroll
            for (int k = 0; k < 3; k++)
                if (g_ok[k])
                    gld_lds16(base + (size_t)g_irow[k] * 1792 + g_half[k] * 1024 + lane * 16,
                              dstb + g_lds[k]);
        }
        const int bufsh = (c & 1) * 11520;
#pragma unroll
        for (int tap = 0; tap < 9; tap++) {
            int rd = c * 9 + tap;
            if (rd < 35) {
                int rn = rd + 1, cn = rn / 9, tn = rn - cn * 9;
                size_t b0 = ((size_t)(tn * 4 + cn) * 16 + cf0) * 1024
                          + (size_t)lane * 16;
#pragma unroll
                for (int g = 0; g < 2; g++) {
                    nx[g][0] = *(const i32x4*)(p2a + b0 + (size_t)g * 1024);
                    nx[g][1] = *(const i32x4*)(p2b + b0 + (size_t)g * 1024);
                    nx[g][2] = *(const i32x4*)(p2c + b0 + (size_t)g * 1024);
                }
            }
            const int kh = tap / 3, kw = tap - kh * 3;
            const int tapoff = kh * 30 + kw;
#pragma unroll
            for (int f = 0; f < 7; f++) {
                int slot = ib[f] + tapoff;
                int sw   = (slot >> 1) & 3;       // == producer rotation f8
                i32x4 bfr = *(const i32x4*)(
                    SB + bufsh + slot * 64 + ((quad ^ sw) * 16));
                __builtin_amdgcn_s_setprio(1);
#pragma unroll
                for (int g = 0; g < 2; g++) {
                    acc[0][g][f] = mfma_i8_64(cw[g][0], bfr, acc[0][g][f]);
                    acc[1][g][f] = mfma_i8_64(cw[g][1], bfr, acc[1][g][f]);
                    acc[2][g][f] = mfma_i8_64(cw[g][2], bfr, acc[2][g][f]);
                }
                __builtin_amdgcn_s_setprio(0);
            }
#pragma unroll
            for (int g = 0; g < 2; g++) {
                cw[g][0] = nx[g][0]; cw[g][1] = nx[g][1]; cw[g][2] = nx[g][2];
            }
        }
        __syncthreads();                          // release buf c, land c+1
    }

#pragma unroll
    for (int g = 0; g < 2; g++)
#pragma unroll
        for (int f = 0; f < 7; f++) {
            int pg = rt * 112 + f * 16 + l15;
#pragma unroll
            for (int reg = 0; reg < 4; reg++) {
                int co = (cf0 + g) * 16 + quad * 4 + reg;
                float A  = (float)acc[0][g][f][reg];
                float Bv = (float)acc[1][g][f][reg];
                float Cv = (float)acc[2][g][f][reg];
                float val = fmaf(A, 65536.f, fmaf(Bv, 256.f, Cv));
                __builtin_nontemporal_store(
                    fmaf(val, scale2[co], bias2[co]),
                    &out[((size_t)n * CO + co) * P + pg]);
            }
        }
}

// ---------------------------------------------------------------------------
// LIF2: in-place over [B=16, T=8, PERT], NT-vectorized (streaming data)
// ---------------------------------------------------------------------------
__global__ __launch_bounds__(256) void k_lif4(const f32x4* __restrict__ in,
                                              f32x4* __restrict__ out)
{
    const int q = PERT / 4;                       // 50176
    const int i = blockIdx.x * 256 + threadIdx.x;
    const int b = i / q;
    const int r = i - b * q;
    const f32x4* pi = in  + (size_t)(b * 8) * q + r;
    f32x4*       po = out + (size_t)(b * 8) * q + r;
    float v0 = 0.f, v1 = 0.f, v2 = 0.f, v3 = 0.f;
#pragma unroll
    for (int t = 0; t < 8; t++) {
        f32x4 xt = __builtin_nontemporal_load(pi + (size_t)t * q);
        f32x4 s;
        v0 = v0 + (xt[0] - v0) * 0.5f; s[0] = (v0 > 1.0f) ? 1.f : 0.f; if (v0 > 1.0f) v0 = 0.f;
        v1 = v1 + (xt[1] - v1) * 0.5f; s[1] = (v1 > 1.0f) ? 1.f : 0.f; if (v1 > 1.0f) v1 = 0.f;
        v2 = v2 + (xt[2] - v2) * 0.5f; s[2] = (v2 > 1.0f) ? 1.f : 0.f; if (v2 > 1.0f) v2 = 0.f;
        v3 = v3 + (xt[3] - v3) * 0.5f; s[3] = (v3 > 1.0f) ? 1.f : 0.f; if (v3 > 1.0f) v3 = 0.f;
        __builtin_nontemporal_store(s, po + (size_t)t * q);
    }
}

extern "C" void kernel_launch(void* const* d_in, const int* in_sizes, int n_in,
                              void* d_out, int out_size, void* d_ws, size_t ws_size,
                              hipStream_t stream) {
    const float* x   = (const float*)d_in[0];
    const float* w1  = (const float*)d_in[1];
    const float* w2  = (const float*)d_in[2];
    const float* wd  = (const float*)d_in[3];
    const float* n1g = (const float*)d_in[4];
    const float* n1b = (const float*)d_in[5];
    const float* n1m = (const float*)d_in[6];
    const float* n1v = (const float*)d_in[7];
    const float* n2g = (const float*)d_in[8];
    const float* n2b = (const float*)d_in[9];
    const float* n2m = (const float*)d_in[10];
    const float* n2v = (const float*)d_in[11];
    const float* ndg = (const float*)d_in[12];
    const float* ndb = (const float*)d_in[13];
    const float* ndm = (const float*)d_in[14];
    const float* ndv = (const float*)d_in[15];

    float* out = (float*)d_out;   // pre1 -> (lif1t) -> pre2 -> final spikes

    // ws layout (1KB-aligned); total ~34.9 MB
    char* w = (char*)d_ws;
    unsigned char*  spike_t = (unsigned char*)w;                     // 25,690,112
    signed char*    p2a     = (signed char*)(w + 25690112);          //    589,824
    signed char*    p2b     = (signed char*)(w + 26279936);          //    589,824
    signed char*    p2c     = (signed char*)(w + 26869760);          //    589,824
    signed char*    pa      = (signed char*)(w + 27459584);          //    294,912
    signed char*    pb      = (signed char*)(w + 27754496);          //    294,912
    signed char*    pc      = (signed char*)(w + 28049408);          //    294,912
    signed char*    pda     = (signed char*)(w + 28344320);          //     32,768
    signed char*    pdb     = (signed char*)(w + 28377088);          //     32,768
    signed char*    pdc     = (signed char*)(w + 28409856);          //     32,768
    float*          qscale1 = (float*)(w + 28442624);
    float*          scale1f = (float*)(w + 28443648);
    float*          qscale2 = (float*)(w + 28444672);
    float*          scale2f = (float*)(w + 28445696);
    float*          bias2   = (float*)(w + 28446720);
    float*          bias1   = (float*)(w + 28447744);
    unsigned int*   xt_p    = (unsigned int*)(w + 28451840);         //  6,422,528

    k_prepA<<<129, 256, 0, stream>>>(
        n1g, n1b, n1m, n1v, n2g, n2b, n2m, n2v, ndg, ndb, ndm, ndv,
        w1, w2, wd, bias1, bias2, qscale1, scale1f, qscale2, scale2f);
    k_prepB<<<224 + (128 * 4 * HWIN) / 256, 256, 0, stream>>>(
        w1, w2, wd, n1g, n1v, n2g, n2v, ndg, ndv, qscale1, qscale2,
        pa, pb, pc, p2a, p2b, p2c, pda, pdb, pdc, x, xt_p);

    k_conv1_mfma<<<dim3(896, 4), 256, 0, stream>>>(
        xt_p, pa, pb, pc, scale1f, bias1, out);
    k_lif1t<<<dim3(16, 4, 49), 256, 0, stream>>>(out, spike_t);
    k_conv2_mfma<<<dim3(896, 2), 256, 0, stream>>>(
        spike_t, xt_p, p2a, p2b, p2c, pda, pdb, pdc, scale2f, bias2, out);
    k_lif4<<<(16 * (PERT / 4)) / 256, 256, 0, stream>>>(
        (const f32x4*)out, (f32x4*)out);
}

// Round 15
// 687.164 us; speedup vs baseline: 1.0027x; 1.0027x over previous
//
#include <hip/hip_runtime.h>

// Problem constants
#define CIN  128
#define CO   256
#define HIN  56
#define WIN  56
#define P    784     // 28*28
#define HWIN 3136    // 56*56
#define PERT 200704  // CO*P

typedef __attribute__((ext_vector_type(4))) float f32x4;
typedef __attribute__((ext_vector_type(4))) int   i32x4;

__device__ __forceinline__ i32x4 mfma_i8_64(i32x4 a, i32x4 b, i32x4 c) {
    return __builtin_amdgcn_mfma_i32_16x16x64_i8(a, b, c, 0, 0, 0);
}

// async global->LDS, 16B per lane; LDS dest = wave-uniform base + lane*16
__device__ __forceinline__ void gld_lds16(const void* g, void* l) {
    __builtin_amdgcn_global_load_lds(
        (const __attribute__((address_space(1))) void*)g,
        (__attribute__((address_space(3))) void*)l, 16, 0, 0);
}

// ---------------------------------------------------------------------------
// prepA (1 launch): bias folds + per-co quant scales for w1 and w2/wd.
// ---------------------------------------------------------------------------
__global__ __launch_bounds__(256) void k_prepA(
    const float* __restrict__ g1, const float* __restrict__ b1,
    const float* __restrict__ m1, const float* __restrict__ v1,
    const float* __restrict__ g2, const float* __restrict__ b2,
    const float* __restrict__ m2, const float* __restrict__ v2,
    const float* __restrict__ gd, const float* __restrict__ bd,
    const float* __restrict__ md, const float* __restrict__ vd,
    const float* __restrict__ w1, const float* __restrict__ w2,
    const float* __restrict__ wd,
    float* __restrict__ bias1, float* __restrict__ bias2,
    float* __restrict__ qscale1, float* __restrict__ scale1,
    float* __restrict__ qscale2, float* __restrict__ scale2)
{
    const int bid = blockIdx.x;
    if (bid == 0) {
        int co = threadIdx.x;
        float inv1 = g1[co] / sqrtf(v1[co] + 1e-5f);
        float inv2 = g2[co] / sqrtf(v2[co] + 1e-5f);
        float invd = gd[co] / sqrtf(vd[co] + 1e-5f);
        bias1[co] = fmaf(-m1[co], inv1, b1[co]);
        bias2[co] = fmaf(-m2[co], inv2, b2[co]) + fmaf(-md[co], invd, bd[co]);
        return;
    }
    const int lane = threadIdx.x & 63;
    if (bid <= 64) {                              // w1 scale: co 0..255
        int co = (bid - 1) * 4 + (threadIdx.x >> 6);
        float iv = g1[co] / sqrtf(v1[co] + 1e-5f);
        float m = 0.f;
        for (int k = lane; k < 1152; k += 64)
            m = fmaxf(m, fabsf(w1[(size_t)co * 1152 + k] * iv));
#pragma unroll
        for (int off = 32; off > 0; off >>= 1)
            m = fmaxf(m, __shfl_xor(m, off));
        if (lane == 0) {
            int s = (int)floorf(log2f(8355000.0f / m));
            if (s > 44) s = 44;
            qscale1[co] = ldexpf(1.0f, s);
            scale1[co]  = ldexpf(1.0f, -s);
        }
    } else {                                      // w2/wd shared scale
        int co = (bid - 65) * 4 + (threadIdx.x >> 6);
        float iv2 = g2[co] / sqrtf(v2[co] + 1e-5f);
        float ivd = gd[co] / sqrtf(vd[co] + 1e-5f);
        float m = 0.f;
        for (int k = lane; k < 2304; k += 64)
            m = fmaxf(m, fabsf(w2[(size_t)co * 2304 + k] * iv2));
        for (int k = lane; k < 128; k += 64)
            m = fmaxf(m, fabsf(wd[(size_t)co * 128 + k] * ivd));
#pragma unroll
        for (int off = 32; off > 0; off >>= 1)
            m = fmaxf(m, __shfl_xor(m, off));
        if (lane == 0) {
            int s = (int)floorf(log2f(8355000.0f / m));
            if (s > 40) s = 40;
            qscale2[co] = ldexpf(1.0f, s);
            scale2[co]  = ldexpf(1.0f, -s);
        }
    }
}

// ---------------------------------------------------------------------------
// prepB (1 launch): i8 digit-plane repacks (w1 / w2 / wd) + input bit-pack.
// W = a*2^16 + b*2^8 + c exactly; per-co power-of-two scale from prepA.
// ---------------------------------------------------------------------------
__global__ __launch_bounds__(256) void k_prepB(
    const float* __restrict__ w1, const float* __restrict__ w2,
    const float* __restrict__ wd,
    const float* __restrict__ n1g, const float* __restrict__ n1v,
    const float* __restrict__ n2g, const float* __restrict__ n2v,
    const float* __restrict__ ndg, const float* __restrict__ ndv,
    const float* __restrict__ qscale1, const float* __restrict__ qscale2,
    signed char* __restrict__ pa, signed char* __restrict__ pb,
    signed char* __restrict__ pc,
    signed char* __restrict__ p2a, signed char* __restrict__ p2b,
    signed char* __restrict__ p2c,
    signed char* __restrict__ pda, signed char* __restrict__ pdb,
    signed char* __restrict__ pdc,
    const float* __restrict__ x, unsigned int* __restrict__ xt_p)
{
    const int bid = blockIdx.x;
    if (bid < 72) {                               // w1 -> [tap9][kg2][cf16][64][16]
        int i = bid * 256 + threadIdx.x;
        if (i >= 18432) return;
        int tap = i >> 11;
        int r   = i & 2047;
        int kg  = r >> 10;
        int r2  = r & 1023;
        int cf  = r2 >> 6;
        int lane = r2 & 63;
        int co  = cf * 16 + (lane & 15);
        int ci0 = kg * 64 + (lane >> 4) * 16;
        float iv = n1g[co] / sqrtf(n1v[co] + 1e-5f);
        float q  = qscale1[co];
#pragma unroll
        for (int j = 0; j < 16; j++) {
            float w = w1[((size_t)co * CIN + ci0 + j) * 9 + tap] * iv;
            int W = __float2int_rn(w * q);
            int d0 = ((W & 0xFF) ^ 0x80) - 0x80;  W = (W - d0) / 256;
            int d1 = ((W & 0xFF) ^ 0x80) - 0x80;  W = (W - d1) / 256;
            size_t idx = (size_t)i * 16 + j;
            pa[idx] = (signed char)W;
            pb[idx] = (signed char)d1;
            pc[idx] = (signed char)d0;
        }
    } else if (bid < 216) {                       // w2 -> [tap9][kg4][cf16][64][16]
        int i = (bid - 72) * 256 + threadIdx.x;
        int tap = i >> 12;
        int r   = i & 4095;
        int kg  = r >> 10;
        int r2  = r & 1023;
        int cf  = r2 >> 6;
        int lane = r2 & 63;
        int co  = cf * 16 + (lane & 15);
        int ci0 = kg * 64 + (lane >> 4) * 16;
        float iv = n2g[co] / sqrtf(n2v[co] + 1e-5f);
        float q  = qscale2[co];
#pragma unroll
        for (int j = 0; j < 16; j++) {
            float w = w2[((size_t)co * CO + ci0 + j) * 9 + tap] * iv;
            int W = __float2int_rn(w * q);
            int d0 = ((W & 0xFF) ^ 0x80) - 0x80;  W = (W - d0) / 256;
            int d1 = ((W & 0xFF) ^ 0x80) - 0x80;  W = (W - d1) / 256;
            size_t idx = (size_t)i * 16 + j;
            p2a[idx] = (signed char)W;
            p2b[idx] = (signed char)d1;
            p2c[idx] = (signed char)d0;
        }
    } else if (bid < 224) {                       // wd -> [kg2][cf16][64][16]
        int i = (bid - 216) * 256 + threadIdx.x;
        int kg  = i >> 10;
        int r2  = i & 1023;
        int cf  = r2 >> 6;
        int lane = r2 & 63;
        int co  = cf * 16 + (lane & 15);
        int ci0 = kg * 64 + (lane >> 4) * 16;
        float iv = ndg[co] / sqrtf(ndv[co] + 1e-5f);
        float q  = qscale2[co];
#pragma unroll
        for (int j = 0; j < 16; j++) {
            float w = wd[(size_t)co * CIN + ci0 + j] * iv;
            int W = __float2int_rn(w * q);
            int d0 = ((W & 0xFF) ^ 0x80) - 0x80;  W = (W - d0) / 256;
            int d1 = ((W & 0xFF) ^ 0x80) - 0x80;  W = (W - d1) / 256;
            size_t idx = (size_t)i * 16 + j;
            pda[idx] = (signed char)W;
            pdb[idx] = (signed char)d1;
            pdc[idx] = (signed char)d0;
        }
    } else {                                      // pack x -> bitmask
        int i = (bid - 224) * 256 + threadIdx.x;  // ((n*4 + w)*3136 + pos)
        int pos = i % HWIN;
        int nw  = i / HWIN;
        int w   = nw & 3;
        int n   = nw >> 2;
        const float* xp = x + ((size_t)n * CIN + w * 32) * HWIN + pos;
        unsigned int word = 0;
#pragma unroll
        for (int ci = 0; ci < 32; ci++)
            if (__builtin_nontemporal_load(&xp[(size_t)ci * HWIN]) != 0.f)
                word |= (1u << ci);
        xt_p[((size_t)n * HWIN + pos) * 4 + w] = word;
    }
}

// ---------------------------------------------------------------------------
// conv1 3x3 s2 p1 via i8 MFMA (K=64) on bit-packed spikes, 3 digit planes.
// R9/R11-verified version (inline nibble-spread, NO swizzle: R13/R14 showed
// the XCD swizzle here couples to conv2 (+50 us there vs -30 here; net loss).
// NT stores keep weights L2-resident.
// ---------------------------------------------------------------------------
__global__ __launch_bounds__(256) void k_conv1_mfma(
    const unsigned int* __restrict__ xt_p,       // [128][3136][4]
    const signed char* __restrict__ pa,          // [9][2][16][64][16]
    const signed char* __restrict__ pb,
    const signed char* __restrict__ pc,
    const float* __restrict__ scale1,
    const float* __restrict__ bias1,
    float* __restrict__ out)                     // [128][256][784] pre-act
{
    __shared__ unsigned int XWP[2][522 * 2];     // [kg][row 9][col 58][2 words]

    const int n    = blockIdx.x / 7;
    const int rt   = blockIdx.x - n * 7;
    const int r0   = rt * 4;
    const int tid  = threadIdx.x;
    const int wave = tid >> 6;
    const int lane = tid & 63;
    const int l15  = lane & 15;
    const int quad = lane >> 4;
    const int cf   = blockIdx.y * 4 + wave;      // one cf (16 co) per wave

    const unsigned int* xp_n = xt_p + (size_t)n * HWIN * 4;
    for (int i = tid; i < 513; i += 256) {
        int row = i / 57, c = i - row * 57;
        int irow = 2 * r0 - 1 + row;             // [-1, 55]
        int iw   = c - 1;                        // [-1, 55]
        uint4 val = {0u, 0u, 0u, 0u};
        if (irow >= 0 && iw >= 0)
            val = *(const uint4*)(xp_n + (size_t)(irow * WIN + iw) * 4);
        int base = row * 58 + c;
        XWP[0][base * 2 + 0] = val.x;            // ci  0..31
        XWP[0][base * 2 + 1] = val.y;            // ci 32..63
        XWP[1][base * 2 + 0] = val.z;            // ci 64..95
        XWP[1][base * 2 + 1] = val.w;            // ci 96..127
    }
    __syncthreads();

    int ib[7];
#pragma unroll
    for (int f = 0; f < 7; f++) {
        int pos = f * 16 + l15;
        int rr = pos / 28, cc = pos - rr * 28;
        ib[f] = (2 * rr) * 58 + 2 * cc;          // + kh*58 + kw per tap
    }

    const int  qh = quad >> 1;                   // which word of the pair
    const int  ql = (quad & 1) * 16;             // bit offset within word

    i32x4 accA[7], accB[7], accC[7];
#pragma unroll
    for (int f = 0; f < 7; f++) {
        accA[f] = (i32x4){0, 0, 0, 0};
        accB[f] = (i32x4){0, 0, 0, 0};
        accC[f] = (i32x4){0, 0, 0, 0};
    }

    i32x4 wa, wb, wc, na, nb, nc;
    {
        size_t b0 = (size_t)cf * 1024 + lane * 16;   // tap=0, kg=0
        wa = *(const i32x4*)(pa + b0);
        wb = *(const i32x4*)(pb + b0);
        wc = *(const i32x4*)(pc + b0);
        na = wa; nb = wb; nc = wc;
    }

#pragma unroll
    for (int kg = 0; kg < 2; kg++) {
#pragma unroll
        for (int tap = 0; tap < 9; tap++) {
            int rd = kg * 9 + tap;
            if (rd < 17) {                       // prefetch next (kg,tap)
                int rn = rd + 1, kn = rn / 9, tn = rn - kn * 9;
                size_t b0 = ((size_t)(tn * 2 + kn) * 16 + cf) * 1024 + lane * 16;
                na = *(const i32x4*)(pa + b0);
                nb = *(const i32x4*)(pb + b0);
                nc = *(const i32x4*)(pc + b0);
            }
            const int kh = tap / 3, kw = tap - kh * 3;
            const int tapoff = kh * 58 + kw;
#pragma unroll
            for (int f = 0; f < 7; f++) {
                int base = ib[f] + tapoff;
                uint2 pr = *(const uint2*)&XWP[kg][base * 2];
                unsigned int w32  = qh ? pr.y : pr.x;
                unsigned int bits = (w32 >> ql) & 0xFFFFu;
                // nibble -> 4 bytes 0/1 spread: (n * 0x00204081) & 0x01010101
                uint4 u;
                u.x = ((bits & 15u)         * 0x00204081u) & 0x01010101u;
                u.y = (((bits >> 4) & 15u)  * 0x00204081u) & 0x01010101u;
                u.z = (((bits >> 8) & 15u)  * 0x00204081u) & 0x01010101u;
                u.w = ((bits >> 12)         * 0x00204081u) & 0x01010101u;
                union { uint4 q; i32x4 v; } cv;
                cv.q = u;
                __builtin_amdgcn_s_setprio(1);
                accA[f] = mfma_i8_64(wa, cv.v, accA[f]);
                accB[f] = mfma_i8_64(wb, cv.v, accB[f]);
                accC[f] = mfma_i8_64(wc, cv.v, accC[f]);
                __builtin_amdgcn_s_setprio(0);
            }
            wa = na; wb = nb; wc = nc;
        }
    }

#pragma unroll
    for (int f = 0; f < 7; f++) {
        int pg = rt * 112 + f * 16 + l15;
#pragma unroll
        for (int reg = 0; reg < 4; reg++) {
            int co = cf * 16 + quad * 4 + reg;
            float hi = (float)accA[f][reg];
            float mi = (float)accB[f][reg];
            float lo = (float)accC[f][reg];
            float val = fmaf(hi, 65536.f, fmaf(mi, 256.f, lo));
            __builtin_nontemporal_store(
                fmaf(val, scale1[co], bias1[co]),
                &out[((size_t)n * CO + co) * P + pg]);
        }
    }
}

// ---------------------------------------------------------------------------
// LIF1 + transpose: pre1 [16][8][256][784] fp32 ->
// spike bytes st [n][kg 4][pos 784][64 ci] u8, with the 4 16B ci-sub-blocks
// of each pos line stored XOR-rotated by f8(pos) = (((oh+1)*30+ow+1)>>1)&3
// so conv2's DMA-landed LDS reads are conflict-free. NT loads on the
// streaming read-once pre1 keep spike_t writes L2-resident for conv2.
// ---------------------------------------------------------------------------
__global__ __launch_bounds__(256) void k_lif1t(
    const float* __restrict__ pre, unsigned char* __restrict__ st)
{
    __shared__ unsigned short T[16 * 68];
    const int b   = blockIdx.x;
    const int co0 = blockIdx.y * 64;
    const int kg  = blockIdx.y;
    const int p0  = blockIdx.z * 16;
    const int tid  = threadIdx.x;
    const int pcol = tid & 15;
    const int g    = tid >> 4;
    const int pos = p0 + g;
    const int oh  = pos / 28, ow = pos - oh * 28;
    const int f8  = ((((oh + 1) * 30 + ow + 1) >> 1) & 3);
    const int no  = (pcol >> 2) ^ f8;            // rotated 16B sub-block
    const int wb  = (pcol & 3) * 4;              // byte offset in sub-block
    float v[4] = {0.f, 0.f, 0.f, 0.f};
    for (int t = 0; t < 8; t++) {
        const float* src = pre + (((size_t)(b * 8 + t)) * CO + co0) * P + p0;
        unsigned short s[4];
#pragma unroll
        for (int j = 0; j < 4; j++) {
            int co = g + 16 * j;
            float xv = __builtin_nontemporal_load(&src[(size_t)co * P + pcol]);
            v[j] = v[j] + (xv - v[j]) * 0.5f;
            bool sp = v[j] > 1.0f;
            s[j] = sp ? 1 : 0;
            if (sp) v[j] = 0.f;
        }
        __syncthreads();
#pragma unroll
        for (int j = 0; j < 4; j++) T[pcol * 68 + g + 16 * j] = s[j];
        __syncthreads();
        unsigned char* dst = st + (((size_t)(b * 8 + t) * 4 + kg) * P + pos) * 64
                               + no * 16 + wb;
        uchar4 ov;
        ov.x = (unsigned char)T[g * 68 + pcol * 4 + 0];
        ov.y = (unsigned char)T[g * 68 + pcol * 4 + 1];
        ov.z = (unsigned char)T[g * 68 + pcol * 4 + 2];
        ov.w = (unsigned char)T[g * 68 + pcol * 4 + 3];
        *(uchar4*)dst = ov;
    }
}

// ---------------------------------------------------------------------------
// conv2 3x3 s1 p1 + ds 1x1 s2 via i8 MFMA (K=64), 3 digit planes, BN folded.
// R11-verified g=2 version (204 us best): full unroll + NT stores + dw-hoist
// + setprio, identity block mapping.
// ---------------------------------------------------------------------------
__global__ __launch_bounds__(256) void k_conv2_mfma(
    const unsigned char* __restrict__ spike_t,   // [128][4][784][64] rotated
    const unsigned int* __restrict__ xt_p,       // [128][3136][4]
    const signed char* __restrict__ p2a,         // [9][4][16][64][16]
    const signed char* __restrict__ p2b,
    const signed char* __restrict__ p2c,
    const signed char* __restrict__ pda,         // [2][16][64][16]
    const signed char* __restrict__ pdb,
    const signed char* __restrict__ pdc,
    const float* __restrict__ scale2,
    const float* __restrict__ bias2,
    float* __restrict__ out)                     // [128][256][784]
{
    __shared__ unsigned char SB[2 * 11520];      // 2 bufs; pos line = 64 B
    __shared__ unsigned int  XW2[4 * 112];       // ds bit-words [word][112 pos]

    const int n    = blockIdx.x / 7;
    const int rt   = blockIdx.x - n * 7;
    const int r0   = rt * 4;
    const int tid  = threadIdx.x;
    const int wave = tid >> 6;
    const int lane = tid & 63;
    const int l15  = lane & 15;
    const int quad = lane >> 4;
    const int cf0  = blockIdx.y * 8 + wave * 2;  // 2 cf (32 co) per wave

    // zero both spike buffers (halo protocol) + stage ds bit-words
    {
        uint4 z = {0u, 0u, 0u, 0u};
        for (int i = tid; i < 1440; i += 256) ((uint4*)SB)[i] = z;
    }
    for (int i = tid; i < 112; i += 256) {
        int r = i / 28, c = i - r * 28;
        uint4 w4 = *(const uint4*)(xt_p + ((size_t)n * HWIN
                    + (2 * (r0 + r)) * WIN + 2 * c) * 4);
        XW2[0 * 112 + i] = w4.x;
        XW2[1 * 112 + i] = w4.y;
        XW2[2 * 112 + i] = w4.z;
        XW2[3 * 112 + i] = w4.w;
    }
    __syncthreads();                              // zeros + XW2 visible

    // ds-phase weight regs FIRST (older than the DMA in vmcnt order, so the
    // ds phase does not wait for the spike DMA queue to drain)
    i32x4 dw0[3][2], dw1[3][2];                  // [plane][g] for kg=0,1
#pragma unroll
    for (int g = 0; g < 2; g++) {
        size_t b0 = ((size_t)cf0 + g) * 1024 + (size_t)lane * 16;
        dw0[0][g] = *(const i32x4*)(pda + b0);
        dw0[1][g] = *(const i32x4*)(pdb + b0);
        dw0[2][g] = *(const i32x4*)(pdc + b0);
        size_t b1 = ((size_t)(16 + cf0) + g) * 1024 + (size_t)lane * 16;
        dw1[0][g] = *(const i32x4*)(pda + b1);
        dw1[1][g] = *(const i32x4*)(pdb + b1);
        dw1[2][g] = *(const i32x4*)(pdc + b1);
    }

    // DMA geometry: idx = wave*3+k in [0,12); row = idx>>1, half = idx&1
    int  g_irow[3], g_lds[3];
    bool g_ok[3];
    int  g_half[3];
#pragma unroll
    for (int k = 0; k < 3; k++) {
        int idx  = wave * 3 + k;
        int row  = idx >> 1, half = idx & 1;
        int irow = r0 - 1 + row;
        g_irow[k] = irow;
        g_half[k] = half;
        g_ok[k]   = ((unsigned)irow < 28u) && (half == 0 || lane < 48);
        g_lds[k]  = row * 1920 + 64 + half * 1024;   // wave-uniform
    }
    const char* sp_n = (const char*)spike_t + (size_t)n * 4 * P * 64;

    // issue chunk-0 DMA now; latency hides under the ds phase below
#pragma unroll
    for (int k = 0; k < 3; k++)
        if (g_ok[k])
            gld_lds16(sp_n + (size_t)g_irow[k] * 1792 + g_half[k] * 1024 + lane * 16,
                      (char*)SB + g_lds[k]);

    int ib[7];
#pragma unroll
    for (int f = 0; f < 7; f++) {
        int pos = f * 16 + l15;
        int rr = pos / 28, cc = pos - rr * 28;
        ib[f] = rr * 30 + cc;                    // + kh*30 + kw per tap
    }

    i32x4 acc[3][2][7];                          // [plane][g][f]
#pragma unroll
    for (int p = 0; p < 3; p++)
#pragma unroll
        for (int g = 0; g < 2; g++)
#pragma unroll
            for (int f = 0; f < 7; f++) acc[p][g][f] = (i32x4){0, 0, 0, 0};

    // ---- ds phase (acc init): bit-unpack from XW2, dw regs die after ----
#pragma unroll
    for (int kg = 0; kg < 2; kg++) {
        const int wsel = (kg * 2 + (quad >> 1)) * 112;
        const int shv  = (quad & 1) * 16;
#pragma unroll
        for (int f = 0; f < 7; f++) {
            unsigned int w32  = XW2[wsel + f * 16 + l15];
            unsigned int bits = (w32 >> shv) & 0xFFFFu;
            uint4 u;
            u.x = ((bits & 15u)         * 0x00204081u) & 0x01010101u;
            u.y = (((bits >> 4) & 15u)  * 0x00204081u) & 0x01010101u;
            u.z = (((bits >> 8) & 15u)  * 0x00204081u) & 0x01010101u;
            u.w = ((bits >> 12)         * 0x00204081u) & 0x01010101u;
            union { uint4 q; i32x4 v; } cv;
            cv.q = u;
            __builtin_amdgcn_s_setprio(1);
#pragma unroll
            for (int g = 0; g < 2; g++) {
                acc[0][g][f] = mfma_i8_64(kg ? dw1[0][g] : dw0[0][g], cv.v, acc[0][g][f]);
                acc[1][g][f] = mfma_i8_64(kg ? dw1[1][g] : dw0[1][g], cv.v, acc[1][g][f]);
                acc[2][g][f] = mfma_i8_64(kg ? dw1[2][g] : dw0[2][g], cv.v, acc[2][g][f]);
            }
            __builtin_amdgcn_s_setprio(0);
        }
    }
    __syncthreads();                              // drains chunk-0 DMA too

    // ---- main conv loop, double-buffered DMA, weight reg prefetch ----
    i32x4 cw[2][3], nx[2][3];
#pragma unroll
    for (int g = 0; g < 2; g++) {
        size_t b0 = ((size_t)(cf0 + g)) * 1024 + (size_t)lane * 16;  // tap0,kg0
        cw[g][0] = *(const i32x4*)(p2a + b0);
        cw[g][1] = *(const i32x4*)(p2b + b0);
        cw[g][2] = *(const i32x4*)(p2c + b0);
        nx[g][0] = cw[g][0]; nx[g][1] = cw[g][1]; nx[g][2] = cw[g][2];
    }

#pragma unroll
    for (int c = 0; c < 4; c++) {
        if (c < 3) {                              // async stage chunk c+1
            const char* base = sp_n + (size_t)(c + 1) * 50176;
            char* dstb = (char*)SB + ((c + 1) & 1) * 11520;
#pragma unroll
            for (int k = 0; k < 3; k++)
                if (g_ok[k])
                    gld_lds16(base + (size_t)g_irow[k] * 1792 + g_half[k] * 1024 + lane * 16,
                              dstb + g_lds[k]);
        }
        const int bufsh = (c & 1) * 11520;
#pragma unroll
        for (int tap = 0; tap < 9; tap++) {
            int rd = c * 9 + tap;
            if (rd < 35) {
                int rn = rd + 1, cn = rn / 9, tn = rn - cn * 9;
                size_t b0 = ((size_t)(tn * 4 + cn) * 16 + cf0) * 1024
                          + (size_t)lane * 16;
#pragma unroll
                for (int g = 0; g < 2; g++) {
                    nx[g][0] = *(const i32x4*)(p2a + b0 + (size_t)g * 1024);
                    nx[g][1] = *(const i32x4*)(p2b + b0 + (size_t)g * 1024);
                    nx[g][2] = *(const i32x4*)(p2c + b0 + (size_t)g * 1024);
                }
            }
            const int kh = tap / 3, kw = tap - kh * 3;
            const int tapoff = kh * 30 + kw;
#pragma unroll
            for (int f = 0; f < 7; f++) {
                int slot = ib[f] + tapoff;
                int sw   = (slot >> 1) & 3;       // == producer rotation f8
                i32x4 bfr = *(const i32x4*)(
                    SB + bufsh + slot * 64 + ((quad ^ sw) * 16));
                __builtin_amdgcn_s_setprio(1);
#pragma unroll
                for (int g = 0; g < 2; g++) {
                    acc[0][g][f] = mfma_i8_64(cw[g][0], bfr, acc[0][g][f]);
                    acc[1][g][f] = mfma_i8_64(cw[g][1], bfr, acc[1][g][f]);
                    acc[2][g][f] = mfma_i8_64(cw[g][2], bfr, acc[2][g][f]);
                }
                __builtin_amdgcn_s_setprio(0);
            }
#pragma unroll
            for (int g = 0; g < 2; g++) {
                cw[g][0] = nx[g][0]; cw[g][1] = nx[g][1]; cw[g][2] = nx[g][2];
            }
        }
        __syncthreads();                          // release buf c, land c+1
    }

#pragma unroll
    for (int g = 0; g < 2; g++)
#pragma unroll
        for (int f = 0; f < 7; f++) {
            int pg = rt * 112 + f * 16 + l15;
#pragma unroll
            for (int reg = 0; reg < 4; reg++) {
                int co = (cf0 + g) * 16 + quad * 4 + reg;
                float A  = (float)acc[0][g][f][reg];
                float Bv = (float)acc[1][g][f][reg];
                float Cv = (float)acc[2][g][f][reg];
                float val = fmaf(A, 65536.f, fmaf(Bv, 256.f, Cv));
                __builtin_nontemporal_store(
                    fmaf(val, scale2[co], bias2[co]),
                    &out[((size_t)n * CO + co) * P + pg]);
            }
        }
}

// ---------------------------------------------------------------------------
// LIF2: in-place over [B=16, T=8, PERT], NT-vectorized (streaming data)
// ---------------------------------------------------------------------------
__global__ __launch_bounds__(256) void k_lif4(const f32x4* __restrict__ in,
                                              f32x4* __restrict__ out)
{
    const int q = PERT / 4;                       // 50176
    const int i = blockIdx.x * 256 + threadIdx.x;
    const int b = i / q;
    const int r = i - b * q;
    const f32x4* pi = in  + (size_t)(b * 8) * q + r;
    f32x4*       po = out + (size_t)(b * 8) * q + r;
    float v0 = 0.f, v1 = 0.f, v2 = 0.f, v3 = 0.f;
#pragma unroll
    for (int t = 0; t < 8; t++) {
        f32x4 xt = __builtin_nontemporal_load(pi + (size_t)t * q);
        f32x4 s;
        v0 = v0 + (xt[0] - v0) * 0.5f; s[0] = (v0 > 1.0f) ? 1.f : 0.f; if (v0 > 1.0f) v0 = 0.f;
        v1 = v1 + (xt[1] - v1) * 0.5f; s[1] = (v1 > 1.0f) ? 1.f : 0.f; if (v1 > 1.0f) v1 = 0.f;
        v2 = v2 + (xt[2] - v2) * 0.5f; s[2] = (v2 > 1.0f) ? 1.f : 0.f; if (v2 > 1.0f) v2 = 0.f;
        v3 = v3 + (xt[3] - v3) * 0.5f; s[3] = (v3 > 1.0f) ? 1.f : 0.f; if (v3 > 1.0f) v3 = 0.f;
        __builtin_nontemporal_store(s, po + (size_t)t * q);
    }
}

extern "C" void kernel_launch(void* const* d_in, const int* in_sizes, int n_in,
                              void* d_out, int out_size, void* d_ws, size_t ws_size,
                              hipStream_t stream) {
    const float* x   = (const float*)d_in[0];
    const float* w1  = (const float*)d_in[1];
    const float* w2  = (const float*)d_in[2];
    const float* wd  = (const float*)d_in[3];
    const float* n1g = (const float*)d_in[4];
    const float* n1b = (const float*)d_in[5];
    const float* n1m = (const float*)d_in[6];
    const float* n1v = (const float*)d_in[7];
    const float* n2g = (const float*)d_in[8];
    const float* n2b = (const float*)d_in[9];
    const float* n2m = (const float*)d_in[10];
    const float* n2v = (const float*)d_in[11];
    const float* ndg = (const float*)d_in[12];
    const float* ndb = (const float*)d_in[13];
    const float* ndm = (const float*)d_in[14];
    const float* ndv = (const float*)d_in[15];

    float* out = (float*)d_out;   // pre1 -> (lif1t) -> pre2 -> final spikes

    // ws layout (1KB-aligned); total ~34.9 MB
    char* w = (char*)d_ws;
    unsigned char*  spike_t = (unsigned char*)w;                     // 25,690,112
    signed char*    p2a     = (signed char*)(w + 25690112);          //    589,824
    signed char*    p2b     = (signed char*)(w + 26279936);          //    589,824
    signed char*    p2c     = (signed char*)(w + 26869760);          //    589,824
    signed char*    pa      = (signed char*)(w + 27459584);          //    294,912
    signed char*    pb      = (signed char*)(w + 27754496);          //    294,912
    signed char*    pc      = (signed char*)(w + 28049408);          //    294,912
    signed char*    pda     = (signed char*)(w + 28344320);          //     32,768
    signed char*    pdb     = (signed char*)(w + 28377088);          //     32,768
    signed char*    pdc     = (signed char*)(w + 28409856);          //     32,768
    float*          qscale1 = (float*)(w + 28442624);
    float*          scale1f = (float*)(w + 28443648);
    float*          qscale2 = (float*)(w + 28444672);
    float*          scale2f = (float*)(w + 28445696);
    float*          bias2   = (float*)(w + 28446720);
    float*          bias1   = (float*)(w + 28447744);
    unsigned int*   xt_p    = (unsigned int*)(w + 28451840);         //  6,422,528

    k_prepA<<<129, 256, 0, stream>>>(
        n1g, n1b, n1m, n1v, n2g, n2b, n2m, n2v, ndg, ndb, ndm, ndv,
        w1, w2, wd, bias1, bias2, qscale1, scale1f, qscale2, scale2f);
    k_prepB<<<224 + (128 * 4 * HWIN) / 256, 256, 0, stream>>>(
        w1, w2, wd, n1g, n1v, n2g, n2v, ndg, ndv, qscale1, qscale2,
        pa, pb, pc, p2a, p2b, p2c, pda, pdb, pdc, x, xt_p);

    k_conv1_mfma<<<dim3(896, 4), 256, 0, stream>>>(
        xt_p, pa, pb, pc, scale1f, bias1, out);
    k_lif1t<<<dim3(16, 4, 49), 256, 0, stream>>>(out, spike_t);
    k_conv2_mfma<<<dim3(896, 2), 256, 0, stream>>>(
        spike_t, xt_p, p2a, p2b, p2c, pda, pdb, pdc, scale2f, bias2, out);
    k_lif4<<<(16 * (PERT / 4)) / 256, 256, 0, stream>>>(
        (const f32x4*)out, (f32x4*)out);
}

// Round 16
// 665.985 us; speedup vs baseline: 1.0345x; 1.0318x over previous
//
#include <hip/hip_runtime.h>

// Problem constants
#define CIN  128
#define CO   256
#define HIN  56
#define WIN  56
#define P    784     // 28*28
#define HWIN 3136    // 56*56
#define PERT 200704  // CO*P

typedef __attribute__((ext_vector_type(4))) float f32x4;
typedef __attribute__((ext_vector_type(4))) int   i32x4;

__device__ __forceinline__ i32x4 mfma_i8_64(i32x4 a, i32x4 b, i32x4 c) {
    return __builtin_amdgcn_mfma_i32_16x16x64_i8(a, b, c, 0, 0, 0);
}

// async global->LDS, 16B per lane; LDS dest = wave-uniform base + lane*16
__device__ __forceinline__ void gld_lds16(const void* g, void* l) {
    __builtin_amdgcn_global_load_lds(
        (const __attribute__((address_space(1))) void*)g,
        (__attribute__((address_space(3))) void*)l, 16, 0, 0);
}

// ---------------------------------------------------------------------------
// prepA (1 launch): bias folds + per-co quant scales for w1 and w2/wd.
// ---------------------------------------------------------------------------
__global__ __launch_bounds__(256) void k_prepA(
    const float* __restrict__ g1, const float* __restrict__ b1,
    const float* __restrict__ m1, const float* __restrict__ v1,
    const float* __restrict__ g2, const float* __restrict__ b2,
    const float* __restrict__ m2, const float* __restrict__ v2,
    const float* __restrict__ gd, const float* __restrict__ bd,
    const float* __restrict__ md, const float* __restrict__ vd,
    const float* __restrict__ w1, const float* __restrict__ w2,
    const float* __restrict__ wd,
    float* __restrict__ bias1, float* __restrict__ bias2,
    float* __restrict__ qscale1, float* __restrict__ scale1,
    float* __restrict__ qscale2, float* __restrict__ scale2)
{
    const int bid = blockIdx.x;
    if (bid == 0) {
        int co = threadIdx.x;
        float inv1 = g1[co] / sqrtf(v1[co] + 1e-5f);
        float inv2 = g2[co] / sqrtf(v2[co] + 1e-5f);
        float invd = gd[co] / sqrtf(vd[co] + 1e-5f);
        bias1[co] = fmaf(-m1[co], inv1, b1[co]);
        bias2[co] = fmaf(-m2[co], inv2, b2[co]) + fmaf(-md[co], invd, bd[co]);
        return;
    }
    const int lane = threadIdx.x & 63;
    if (bid <= 64) {                              // w1 scale: co 0..255
        int co = (bid - 1) * 4 + (threadIdx.x >> 6);
        float iv = g1[co] / sqrtf(v1[co] + 1e-5f);
        float m = 0.f;
        for (int k = lane; k < 1152; k += 64)
            m = fmaxf(m, fabsf(w1[(size_t)co * 1152 + k] * iv));
#pragma unroll
        for (int off = 32; off > 0; off >>= 1)
            m = fmaxf(m, __shfl_xor(m, off));
        if (lane == 0) {
            int s = (int)floorf(log2f(8355000.0f / m));
            if (s > 44) s = 44;
            qscale1[co] = ldexpf(1.0f, s);
            scale1[co]  = ldexpf(1.0f, -s);
        }
    } else {                                      // w2/wd shared scale
        int co = (bid - 65) * 4 + (threadIdx.x >> 6);
        float iv2 = g2[co] / sqrtf(v2[co] + 1e-5f);
        float ivd = gd[co] / sqrtf(vd[co] + 1e-5f);
        float m = 0.f;
        for (int k = lane; k < 2304; k += 64)
            m = fmaxf(m, fabsf(w2[(size_t)co * 2304 + k] * iv2));
        for (int k = lane; k < 128; k += 64)
            m = fmaxf(m, fabsf(wd[(size_t)co * 128 + k] * ivd));
#pragma unroll
        for (int off = 32; off > 0; off >>= 1)
            m = fmaxf(m, __shfl_xor(m, off));
        if (lane == 0) {
            int s = (int)floorf(log2f(8355000.0f / m));
            if (s > 40) s = 40;
            qscale2[co] = ldexpf(1.0f, s);
            scale2[co]  = ldexpf(1.0f, -s);
        }
    }
}

// ---------------------------------------------------------------------------
// prepB (1 launch): i8 digit-plane repacks (w1 / w2 / wd) + input bit-pack.
// W = a*2^16 + b*2^8 + c exactly; per-co power-of-two scale from prepA.
// ---------------------------------------------------------------------------
__global__ __launch_bounds__(256) void k_prepB(
    const float* __restrict__ w1, const float* __restrict__ w2,
    const float* __restrict__ wd,
    const float* __restrict__ n1g, const float* __restrict__ n1v,
    const float* __restrict__ n2g, const float* __restrict__ n2v,
    const float* __restrict__ ndg, const float* __restrict__ ndv,
    const float* __restrict__ qscale1, const float* __restrict__ qscale2,
    signed char* __restrict__ pa, signed char* __restrict__ pb,
    signed char* __restrict__ pc,
    signed char* __restrict__ p2a, signed char* __restrict__ p2b,
    signed char* __restrict__ p2c,
    signed char* __restrict__ pda, signed char* __restrict__ pdb,
    signed char* __restrict__ pdc,
    const float* __restrict__ x, unsigned int* __restrict__ xt_p)
{
    const int bid = blockIdx.x;
    if (bid < 72) {                               // w1 -> [tap9][kg2][cf16][64][16]
        int i = bid * 256 + threadIdx.x;
        if (i >= 18432) return;
        int tap = i >> 11;
        int r   = i & 2047;
        int kg  = r >> 10;
        int r2  = r & 1023;
        int cf  = r2 >> 6;
        int lane = r2 & 63;
        int co  = cf * 16 + (lane & 15);
        int ci0 = kg * 64 + (lane >> 4) * 16;
        float iv = n1g[co] / sqrtf(n1v[co] + 1e-5f);
        float q  = qscale1[co];
#pragma unroll
        for (int j = 0; j < 16; j++) {
            float w = w1[((size_t)co * CIN + ci0 + j) * 9 + tap] * iv;
            int W = __float2int_rn(w * q);
            int d0 = ((W & 0xFF) ^ 0x80) - 0x80;  W = (W - d0) / 256;
            int d1 = ((W & 0xFF) ^ 0x80) - 0x80;  W = (W - d1) / 256;
            size_t idx = (size_t)i * 16 + j;
            pa[idx] = (signed char)W;
            pb[idx] = (signed char)d1;
            pc[idx] = (signed char)d0;
        }
    } else if (bid < 216) {                       // w2 -> [tap9][kg4][cf16][64][16]
        int i = (bid - 72) * 256 + threadIdx.x;
        int tap = i >> 12;
        int r   = i & 4095;
        int kg  = r >> 10;
        int r2  = r & 1023;
        int cf  = r2 >> 6;
        int lane = r2 & 63;
        int co  = cf * 16 + (lane & 15);
        int ci0 = kg * 64 + (lane >> 4) * 16;
        float iv = n2g[co] / sqrtf(n2v[co] + 1e-5f);
        float q  = qscale2[co];
#pragma unroll
        for (int j = 0; j < 16; j++) {
            float w = w2[((size_t)co * CO + ci0 + j) * 9 + tap] * iv;
            int W = __float2int_rn(w * q);
            int d0 = ((W & 0xFF) ^ 0x80) - 0x80;  W = (W - d0) / 256;
            int d1 = ((W & 0xFF) ^ 0x80) - 0x80;  W = (W - d1) / 256;
            size_t idx = (size_t)i * 16 + j;
            p2a[idx] = (signed char)W;
            p2b[idx] = (signed char)d1;
            p2c[idx] = (signed char)d0;
        }
    } else if (bid < 224) {                       // wd -> [kg2][cf16][64][16]
        int i = (bid - 216) * 256 + threadIdx.x;
        int kg  = i >> 10;
        int r2  = i & 1023;
        int cf  = r2 >> 6;
        int lane = r2 & 63;
        int co  = cf * 16 + (lane & 15);
        int ci0 = kg * 64 + (lane >> 4) * 16;
        float iv = ndg[co] / sqrtf(ndv[co] + 1e-5f);
        float q  = qscale2[co];
#pragma unroll
        for (int j = 0; j < 16; j++) {
            float w = wd[(size_t)co * CIN + ci0 + j] * iv;
            int W = __float2int_rn(w * q);
            int d0 = ((W & 0xFF) ^ 0x80) - 0x80;  W = (W - d0) / 256;
            int d1 = ((W & 0xFF) ^ 0x80) - 0x80;  W = (W - d1) / 256;
            size_t idx = (size_t)i * 16 + j;
            pda[idx] = (signed char)W;
            pdb[idx] = (signed char)d1;
            pdc[idx] = (signed char)d0;
        }
    } else {                                      // pack x -> bitmask
        int i = (bid - 224) * 256 + threadIdx.x;  // ((n*4 + w)*3136 + pos)
        int pos = i % HWIN;
        int nw  = i / HWIN;
        int w   = nw & 3;
        int n   = nw >> 2;
        const float* xp = x + ((size_t)n * CIN + w * 32) * HWIN + pos;
        unsigned int word = 0;
#pragma unroll
        for (int ci = 0; ci < 32; ci++)
            if (__builtin_nontemporal_load(&xp[(size_t)ci * HWIN]) != 0.f)
                word |= (1u << ci);
        xt_p[((size_t)n * HWIN + pos) * 4 + w] = word;
    }
}

// ---------------------------------------------------------------------------
// conv1 3x3 s2 p1 via i8 MFMA (K=64) on bit-packed spikes, 3 digit planes.
// R9/R11-verified version (inline nibble-spread, identity mapping).
// NT stores keep weights L2-resident.
// ---------------------------------------------------------------------------
__global__ __launch_bounds__(256) void k_conv1_mfma(
    const unsigned int* __restrict__ xt_p,       // [128][3136][4]
    const signed char* __restrict__ pa,          // [9][2][16][64][16]
    const signed char* __restrict__ pb,
    const signed char* __restrict__ pc,
    const float* __restrict__ scale1,
    const float* __restrict__ bias1,
    float* __restrict__ out)                     // [128][256][784] pre-act
{
    __shared__ unsigned int XWP[2][522 * 2];     // [kg][row 9][col 58][2 words]

    const int n    = blockIdx.x / 7;
    const int rt   = blockIdx.x - n * 7;
    const int r0   = rt * 4;
    const int tid  = threadIdx.x;
    const int wave = tid >> 6;
    const int lane = tid & 63;
    const int l15  = lane & 15;
    const int quad = lane >> 4;
    const int cf   = blockIdx.y * 4 + wave;      // one cf (16 co) per wave

    const unsigned int* xp_n = xt_p + (size_t)n * HWIN * 4;
    for (int i = tid; i < 513; i += 256) {
        int row = i / 57, c = i - row * 57;
        int irow = 2 * r0 - 1 + row;             // [-1, 55]
        int iw   = c - 1;                        // [-1, 55]
        uint4 val = {0u, 0u, 0u, 0u};
        if (irow >= 0 && iw >= 0)
            val = *(const uint4*)(xp_n + (size_t)(irow * WIN + iw) * 4);
        int base = row * 58 + c;
        XWP[0][base * 2 + 0] = val.x;            // ci  0..31
        XWP[0][base * 2 + 1] = val.y;            // ci 32..63
        XWP[1][base * 2 + 0] = val.z;            // ci 64..95
        XWP[1][base * 2 + 1] = val.w;            // ci 96..127
    }
    __syncthreads();

    int ib[7];
#pragma unroll
    for (int f = 0; f < 7; f++) {
        int pos = f * 16 + l15;
        int rr = pos / 28, cc = pos - rr * 28;
        ib[f] = (2 * rr) * 58 + 2 * cc;          // + kh*58 + kw per tap
    }

    const int  qh = quad >> 1;                   // which word of the pair
    const int  ql = (quad & 1) * 16;             // bit offset within word

    i32x4 accA[7], accB[7], accC[7];
#pragma unroll
    for (int f = 0; f < 7; f++) {
        accA[f] = (i32x4){0, 0, 0, 0};
        accB[f] = (i32x4){0, 0, 0, 0};
        accC[f] = (i32x4){0, 0, 0, 0};
    }

    i32x4 wa, wb, wc, na, nb, nc;
    {
        size_t b0 = (size_t)cf * 1024 + lane * 16;   // tap=0, kg=0
        wa = *(const i32x4*)(pa + b0);
        wb = *(const i32x4*)(pb + b0);
        wc = *(const i32x4*)(pc + b0);
        na = wa; nb = wb; nc = wc;
    }

#pragma unroll
    for (int kg = 0; kg < 2; kg++) {
#pragma unroll
        for (int tap = 0; tap < 9; tap++) {
            int rd = kg * 9 + tap;
            if (rd < 17) {                       // prefetch next (kg,tap)
                int rn = rd + 1, kn = rn / 9, tn = rn - kn * 9;
                size_t b0 = ((size_t)(tn * 2 + kn) * 16 + cf) * 1024 + lane * 16;
                na = *(const i32x4*)(pa + b0);
                nb = *(const i32x4*)(pb + b0);
                nc = *(const i32x4*)(pc + b0);
            }
            const int kh = tap / 3, kw = tap - kh * 3;
            const int tapoff = kh * 58 + kw;
#pragma unroll
            for (int f = 0; f < 7; f++) {
                int base = ib[f] + tapoff;
                uint2 pr = *(const uint2*)&XWP[kg][base * 2];
                unsigned int w32  = qh ? pr.y : pr.x;
                unsigned int bits = (w32 >> ql) & 0xFFFFu;
                // nibble -> 4 bytes 0/1 spread: (n * 0x00204081) & 0x01010101
                uint4 u;
                u.x = ((bits & 15u)         * 0x00204081u) & 0x01010101u;
                u.y = (((bits >> 4) & 15u)  * 0x00204081u) & 0x01010101u;
                u.z = (((bits >> 8) & 15u)  * 0x00204081u) & 0x01010101u;
                u.w = ((bits >> 12)         * 0x00204081u) & 0x01010101u;
                union { uint4 q; i32x4 v; } cv;
                cv.q = u;
                __builtin_amdgcn_s_setprio(1);
                accA[f] = mfma_i8_64(wa, cv.v, accA[f]);
                accB[f] = mfma_i8_64(wb, cv.v, accB[f]);
                accC[f] = mfma_i8_64(wc, cv.v, accC[f]);
                __builtin_amdgcn_s_setprio(0);
            }
            wa = na; wb = nb; wc = nc;
        }
    }

#pragma unroll
    for (int f = 0; f < 7; f++) {
        int pg = rt * 112 + f * 16 + l15;
#pragma unroll
        for (int reg = 0; reg < 4; reg++) {
            int co = cf * 16 + quad * 4 + reg;
            float hi = (float)accA[f][reg];
            float mi = (float)accB[f][reg];
            float lo = (float)accC[f][reg];
            float val = fmaf(hi, 65536.f, fmaf(mi, 256.f, lo));
            __builtin_nontemporal_store(
                fmaf(val, scale1[co], bias1[co]),
                &out[((size_t)n * CO + co) * P + pg]);
        }
    }
}

// ---------------------------------------------------------------------------
// LIF1 + transpose: pre1 [16][8][256][784] fp32 ->
// spike bytes st [n][kg 4][pos 784][64 ci] u8, with the 4 16B ci-sub-blocks
// of each pos line stored XOR-rotated by f8(pos) = (((oh+1)*30+ow+1)>>1)&3
// so conv2's DMA-landed LDS reads are conflict-free. NT loads on the
// streaming read-once pre1 keep spike_t writes L2-resident for conv2.
// ---------------------------------------------------------------------------
__global__ __launch_bounds__(256) void k_lif1t(
    const float* __restrict__ pre, unsigned char* __restrict__ st)
{
    __shared__ unsigned short T[16 * 68];
    const int b   = blockIdx.x;
    const int co0 = blockIdx.y * 64;
    const int kg  = blockIdx.y;
    const int p0  = blockIdx.z * 16;
    const int tid  = threadIdx.x;
    const int pcol = tid & 15;
    const int g    = tid >> 4;
    const int pos = p0 + g;
    const int oh  = pos / 28, ow = pos - oh * 28;
    const int f8  = ((((oh + 1) * 30 + ow + 1) >> 1) & 3);
    const int no  = (pcol >> 2) ^ f8;            // rotated 16B sub-block
    const int wb  = (pcol & 3) * 4;              // byte offset in sub-block
    float v[4] = {0.f, 0.f, 0.f, 0.f};
    for (int t = 0; t < 8; t++) {
        const float* src = pre + (((size_t)(b * 8 + t)) * CO + co0) * P + p0;
        unsigned short s[4];
#pragma unroll
        for (int j = 0; j < 4; j++) {
            int co = g + 16 * j;
            float xv = __builtin_nontemporal_load(&src[(size_t)co * P + pcol]);
            v[j] = v[j] + (xv - v[j]) * 0.5f;
            bool sp = v[j] > 1.0f;
            s[j] = sp ? 1 : 0;
            if (sp) v[j] = 0.f;
        }
        __syncthreads();
#pragma unroll
        for (int j = 0; j < 4; j++) T[pcol * 68 + g + 16 * j] = s[j];
        __syncthreads();
        unsigned char* dst = st + (((size_t)(b * 8 + t) * 4 + kg) * P + pos) * 64
                               + no * 16 + wb;
        uchar4 ov;
        ov.x = (unsigned char)T[g * 68 + pcol * 4 + 0];
        ov.y = (unsigned char)T[g * 68 + pcol * 4 + 1];
        ov.z = (unsigned char)T[g * 68 + pcol * 4 + 2];
        ov.w = (unsigned char)T[g * 68 + pcol * 4 + 3];
        *(uchar4*)dst = ov;
    }
}

// ---------------------------------------------------------------------------
// conv2 3x3 s1 p1 + ds 1x1 s2 via i8 MFMA (K=64), 3 digit planes, BN folded.
// R11-verified g=2 version: full unroll + NT stores + dw-hoist + setprio,
// identity block mapping. Session-state note: this exact kernel measures
// 204-209 us on fast-state sessions (R9/R11) and 254-256 us on slow-state
// sessions (R13-R15) with identical FETCH/WRITE/conflict counters — the
// difference is chip clock state, not code.
// ---------------------------------------------------------------------------
__global__ __launch_bounds__(256) void k_conv2_mfma(
    const unsigned char* __restrict__ spike_t,   // [128][4][784][64] rotated
    const unsigned int* __restrict__ xt_p,       // [128][3136][4]
    const signed char* __restrict__ p2a,         // [9][4][16][64][16]
    const signed char* __restrict__ p2b,
    const signed char* __restrict__ p2c,
    const signed char* __restrict__ pda,         // [2][16][64][16]
    const signed char* __restrict__ pdb,
    const signed char* __restrict__ pdc,
    const float* __restrict__ scale2,
    const float* __restrict__ bias2,
    float* __restrict__ out)                     // [128][256][784]
{
    __shared__ unsigned char SB[2 * 11520];      // 2 bufs; pos line = 64 B
    __shared__ unsigned int  XW2[4 * 112];       // ds bit-words [word][112 pos]

    const int n    = blockIdx.x / 7;
    const int rt   = blockIdx.x - n * 7;
    const int r0   = rt * 4;
    const int tid  = threadIdx.x;
    const int wave = tid >> 6;
    const int lane = tid & 63;
    const int l15  = lane & 15;
    const int quad = lane >> 4;
    const int cf0  = blockIdx.y * 8 + wave * 2;  // 2 cf (32 co) per wave

    // zero both spike buffers (halo protocol) + stage ds bit-words
    {
        uint4 z = {0u, 0u, 0u, 0u};
        for (int i = tid; i < 1440; i += 256) ((uint4*)SB)[i] = z;
    }
    for (int i = tid; i < 112; i += 256) {
        int r = i / 28, c = i - r * 28;
        uint4 w4 = *(const uint4*)(xt_p + ((size_t)n * HWIN
                    + (2 * (r0 + r)) * WIN + 2 * c) * 4);
        XW2[0 * 112 + i] = w4.x;
        XW2[1 * 112 + i] = w4.y;
        XW2[2 * 112 + i] = w4.z;
        XW2[3 * 112 + i] = w4.w;
    }
    __syncthreads();                              // zeros + XW2 visible

    // ds-phase weight regs FIRST (older than the DMA in vmcnt order, so the
    // ds phase does not wait for the spike DMA queue to drain)
    i32x4 dw0[3][2], dw1[3][2];                  // [plane][g] for kg=0,1
#pragma unroll
    for (int g = 0; g < 2; g++) {
        size_t b0 = ((size_t)cf0 + g) * 1024 + (size_t)lane * 16;
        dw0[0][g] = *(const i32x4*)(pda + b0);
        dw0[1][g] = *(const i32x4*)(pdb + b0);
        dw0[2][g] = *(const i32x4*)(pdc + b0);
        size_t b1 = ((size_t)(16 + cf0) + g) * 1024 + (size_t)lane * 16;
        dw1[0][g] = *(const i32x4*)(pda + b1);
        dw1[1][g] = *(const i32x4*)(pdb + b1);
        dw1[2][g] = *(const i32x4*)(pdc + b1);
    }

    // DMA geometry: idx = wave*3+k in [0,12); row = idx>>1, half = idx&1
    int  g_irow[3], g_lds[3];
    bool g_ok[3];
    int  g_half[3];
#pragma unroll
    for (int k = 0; k < 3; k++) {
        int idx  = wave * 3 + k;
        int row  = idx >> 1, half = idx & 1;
        int irow = r0 - 1 + row;
        g_irow[k] = irow;
        g_half[k] = half;
        g_ok[k]   = ((unsigned)irow < 28u) && (half == 0 || lane < 48);
        g_lds[k]  = row * 1920 + 64 + half * 1024;   // wave-uniform
    }
    const char* sp_n = (const char*)spike_t + (size_t)n * 4 * P * 64;

    // issue chunk-0 DMA now; latency hides under the ds phase below
#pragma unroll
    for (int k = 0; k < 3; k++)
        if (g_ok[k])
            gld_lds16(sp_n + (size_t)g_irow[k] * 1792 + g_half[k] * 1024 + lane * 16,
                      (char*)SB + g_lds[k]);

    int ib[7];
#pragma unroll
    for (int f = 0; f < 7; f++) {
        int pos = f * 16 + l15;
        int rr = pos / 28, cc = pos - rr * 28;
        ib[f] = rr * 30 + cc;                    // + kh*30 + kw per tap
    }

    i32x4 acc[3][2][7];                          // [plane][g][f]
#pragma unroll
    for (int p = 0; p < 3; p++)
#pragma unroll
        for (int g = 0; g < 2; g++)
#pragma unroll
            for (int f = 0; f < 7; f++) acc[p][g][f] = (i32x4){0, 0, 0, 0};

    // ---- ds phase (acc init): bit-unpack from XW2, dw regs die after ----
#pragma unroll
    for (int kg = 0; kg < 2; kg++) {
        const int wsel = (kg * 2 + (quad >> 1)) * 112;
        const int shv  = (quad & 1) * 16;
#pragma unroll
        for (int f = 0; f < 7; f++) {
            unsigned int w32  = XW2[wsel + f * 16 + l15];
            unsigned int bits = (w32 >> shv) & 0xFFFFu;
            uint4 u;
            u.x = ((bits & 15u)         * 0x00204081u) & 0x01010101u;
            u.y = (((bits >> 4) & 15u)  * 0x00204081u) & 0x01010101u;
            u.z = (((bits >> 8) & 15u)  * 0x00204081u) & 0x01010101u;
            u.w = ((bits >> 12)         * 0x00204081u) & 0x01010101u;
            union { uint4 q; i32x4 v; } cv;
            cv.q = u;
            __builtin_amdgcn_s_setprio(1);
#pragma unroll
            for (int g = 0; g < 2; g++) {
                acc[0][g][f] = mfma_i8_64(kg ? dw1[0][g] : dw0[0][g], cv.v, acc[0][g][f]);
                acc[1][g][f] = mfma_i8_64(kg ? dw1[1][g] : dw0[1][g], cv.v, acc[1][g][f]);
                acc[2][g][f] = mfma_i8_64(kg ? dw1[2][g] : dw0[2][g], cv.v, acc[2][g][f]);
            }
            __builtin_amdgcn_s_setprio(0);
        }
    }
    __syncthreads();                              // drains chunk-0 DMA too

    // ---- main conv loop, double-buffered DMA, weight reg prefetch ----
    i32x4 cw[2][3], nx[2][3];
#pragma unroll
    for (int g = 0; g < 2; g++) {
        size_t b0 = ((size_t)(cf0 + g)) * 1024 + (size_t)lane * 16;  // tap0,kg0
        cw[g][0] = *(const i32x4*)(p2a + b0);
        cw[g][1] = *(const i32x4*)(p2b + b0);
        cw[g][2] = *(const i32x4*)(p2c + b0);
        nx[g][0] = cw[g][0]; nx[g][1] = cw[g][1]; nx[g][2] = cw[g][2];
    }

#pragma unroll
    for (int c = 0; c < 4; c++) {
        if (c < 3) {                              // async stage chunk c+1
            const char* base = sp_n + (size_t)(c + 1) * 50176;
            char* dstb = (char*)SB + ((c + 1) & 1) * 11520;
#pragma unroll
            for (int k = 0; k < 3; k++)
                if (g_ok[k])
                    gld_lds16(base + (size_t)g_irow[k] * 1792 + g_half[k] * 1024 + lane * 16,
                              dstb + g_lds[k]);
        }
        const int bufsh = (c & 1) * 11520;
#pragma unroll
        for (int tap = 0; tap < 9; tap++) {
            int rd = c * 9 + tap;
            if (rd < 35) {
                int rn = rd + 1, cn = rn / 9, tn = rn - cn * 9;
                size_t b0 = ((size_t)(tn * 4 + cn) * 16 + cf0) * 1024
                          + (size_t)lane * 16;
#pragma unroll
                for (int g = 0; g < 2; g++) {
                    nx[g][0] = *(const i32x4*)(p2a + b0 + (size_t)g * 1024);
                    nx[g][1] = *(const i32x4*)(p2b + b0 + (size_t)g * 1024);
                    nx[g][2] = *(const i32x4*)(p2c + b0 + (size_t)g * 1024);
                }
            }
            const int kh = tap / 3, kw = tap - kh * 3;
            const int tapoff = kh * 30 + kw;
#pragma unroll
            for (int f = 0; f < 7; f++) {
                int slot = ib[f] + tapoff;
                int sw   = (slot >> 1) & 3;       // == producer rotation f8
                i32x4 bfr = *(const i32x4*)(
                    SB + bufsh + slot * 64 + ((quad ^ sw) * 16));
                __builtin_amdgcn_s_setprio(1);
#pragma unroll
                for (int g = 0; g < 2; g++) {
                    acc[0][g][f] = mfma_i8_64(cw[g][0], bfr, acc[0][g][f]);
                    acc[1][g][f] = mfma_i8_64(cw[g][1], bfr, acc[1][g][f]);
                    acc[2][g][f] = mfma_i8_64(cw[g][2], bfr, acc[2][g][f]);
                }
                __builtin_amdgcn_s_setprio(0);
            }
#pragma unroll
            for (int g = 0; g < 2; g++) {
                cw[g][0] = nx[g][0]; cw[g][1] = nx[g][1]; cw[g][2] = nx[g][2];
            }
        }
        __syncthreads();                          // release buf c, land c+1
    }

#pragma unroll
    for (int g = 0; g < 2; g++)
#pragma unroll
        for (int f = 0; f < 7; f++) {
            int pg = rt * 112 + f * 16 + l15;
#pragma unroll
            for (int reg = 0; reg < 4; reg++) {
                int co = (cf0 + g) * 16 + quad * 4 + reg;
                float A  = (float)acc[0][g][f][reg];
                float Bv = (float)acc[1][g][f][reg];
                float Cv = (float)acc[2][g][f][reg];
                float val = fmaf(A, 65536.f, fmaf(Bv, 256.f, Cv));
                __builtin_nontemporal_store(
                    fmaf(val, scale2[co], bias2[co]),
                    &out[((size_t)n * CO + co) * P + pg]);
            }
        }
}

// ---------------------------------------------------------------------------
// LIF2: in-place over [B=16, T=8, PERT], NT-vectorized (streaming data)
// ---------------------------------------------------------------------------
__global__ __launch_bounds__(256) void k_lif4(const f32x4* __restrict__ in,
                                              f32x4* __restrict__ out)
{
    const int q = PERT / 4;                       // 50176
    const int i = blockIdx.x * 256 + threadIdx.x;
    const int b = i / q;
    const int r = i - b * q;
    const f32x4* pi = in  + (size_t)(b * 8) * q + r;
    f32x4*       po = out + (size_t)(b * 8) * q + r;
    float v0 = 0.f, v1 = 0.f, v2 = 0.f, v3 = 0.f;
#pragma unroll
    for (int t = 0; t < 8; t++) {
        f32x4 xt = __builtin_nontemporal_load(pi + (size_t)t * q);
        f32x4 s;
        v0 = v0 + (xt[0] - v0) * 0.5f; s[0] = (v0 > 1.0f) ? 1.f : 0.f; if (v0 > 1.0f) v0 = 0.f;
        v1 = v1 + (xt[1] - v1) * 0.5f; s[1] = (v1 > 1.0f) ? 1.f : 0.f; if (v1 > 1.0f) v1 = 0.f;
        v2 = v2 + (xt[2] - v2) * 0.5f; s[2] = (v2 > 1.0f) ? 1.f : 0.f; if (v2 > 1.0f) v2 = 0.f;
        v3 = v3 + (xt[3] - v3) * 0.5f; s[3] = (v3 > 1.0f) ? 1.f : 0.f; if (v3 > 1.0f) v3 = 0.f;
        __builtin_nontemporal_store(s, po + (size_t)t * q);
    }
}

extern "C" void kernel_launch(void* const* d_in, const int* in_sizes, int n_in,
                              void* d_out, int out_size, void* d_ws, size_t ws_size,
                              hipStream_t stream) {
    const float* x   = (const float*)d_in[0];
    const float* w1  = (const float*)d_in[1];
    const float* w2  = (const float*)d_in[2];
    const float* wd  = (const float*)d_in[3];
    const float* n1g = (const float*)d_in[4];
    const float* n1b = (const float*)d_in[5];
    const float* n1m = (const float*)d_in[6];
    const float* n1v = (const float*)d_in[7];
    const float* n2g = (const float*)d_in[8];
    const float* n2b = (const float*)d_in[9];
    const float* n2m = (const float*)d_in[10];
    const float* n2v = (const float*)d_in[11];
    const float* ndg = (const float*)d_in[12];
    const float* ndb = (const float*)d_in[13];
    const float* ndm = (const float*)d_in[14];
    const float* ndv = (const float*)d_in[15];

    float* out = (float*)d_out;   // pre1 -> (lif1t) -> pre2 -> final spikes

    // ws layout (1KB-aligned); total ~34.9 MB
    char* w = (char*)d_ws;
    unsigned char*  spike_t = (unsigned char*)w;                     // 25,690,112
    signed char*    p2a     = (signed char*)(w + 25690112);          //    589,824
    signed char*    p2b     = (signed char*)(w + 26279936);          //    589,824
    signed char*    p2c     = (signed char*)(w + 26869760);          //    589,824
    signed char*    pa      = (signed char*)(w + 27459584);          //    294,912
    signed char*    pb      = (signed char*)(w + 27754496);          //    294,912
    signed char*    pc      = (signed char*)(w + 28049408);          //    294,912
    signed char*    pda     = (signed char*)(w + 28344320);          //     32,768
    signed char*    pdb     = (signed char*)(w + 28377088);          //     32,768
    signed char*    pdc     = (signed char*)(w + 28409856);          //     32,768
    float*          qscale1 = (float*)(w + 28442624);
    float*          scale1f = (float*)(w + 28443648);
    float*          qscale2 = (float*)(w + 28444672);
    float*          scale2f = (float*)(w + 28445696);
    float*          bias2   = (float*)(w + 28446720);
    float*          bias1   = (float*)(w + 28447744);
    unsigned int*   xt_p    = (unsigned int*)(w + 28451840);         //  6,422,528

    k_prepA<<<129, 256, 0, stream>>>(
        n1g, n1b, n1m, n1v, n2g, n2b, n2m, n2v, ndg, ndb, ndm, ndv,
        w1, w2, wd, bias1, bias2, qscale1, scale1f, qscale2, scale2f);
    k_prepB<<<224 + (128 * 4 * HWIN) / 256, 256, 0, stream>>>(
        w1, w2, wd, n1g, n1v, n2g, n2v, ndg, ndv, qscale1, qscale2,
        pa, pb, pc, p2a, p2b, p2c, pda, pdb, pdc, x, xt_p);

    k_conv1_mfma<<<dim3(896, 4), 256, 0, stream>>>(
        xt_p, pa, pb, pc, scale1f, bias1, out);
    k_lif1t<<<dim3(16, 4, 49), 256, 0, stream>>>(out, spike_t);
    k_conv2_mfma<<<dim3(896, 2), 256, 0, stream>>>(
        spike_t, xt_p, p2a, p2b, p2c, pda, pdb, pdc, scale2f, bias2, out);
    k_lif4<<<(16 * (PERT / 4)) / 256, 256, 0, stream>>>(
        (const f32x4*)out, (f32x4*)out);
}